// Round 3
// baseline (1571.295 us; speedup 1.0000x reference)
//
#include <hip/hip_runtime.h>
#include <hip/hip_bf16.h>
#include <math.h>

#define N_NODES 100000
#define N_EDGES 1000000
#define NEG_SLOPE 0.2f
#define SCAN_NB 98  // ceil(100000/1024)

__device__ inline unsigned pack_bf16(float a, float b) {
    unsigned ua = __float_as_uint(a);
    unsigned ub = __float_as_uint(b);
    // round-to-nearest-even
    ua = (ua + 0x7FFFu + ((ua >> 16) & 1u)) >> 16;
    ub = (ub + 0x7FFFu + ((ub >> 16) & 1u)) >> 16;
    return ua | (ub << 16);
}

// ---------------- CSR build ----------------
__global__ void hist_kernel(const int* __restrict__ dst, int* __restrict__ counts) {
    int e = blockIdx.x * blockDim.x + threadIdx.x;
    if (e < N_EDGES) atomicAdd(&counts[dst[e]], 1);
}

__global__ void scan_partial(const int* __restrict__ counts, int* __restrict__ bsum) {
    __shared__ int red[256];
    int b = blockIdx.x;
    int base = b * 1024;
    int s = 0;
    for (int i = threadIdx.x; i < 1024; i += 256) {
        int gi = base + i;
        s += (gi < N_NODES) ? counts[gi] : 0;
    }
    red[threadIdx.x] = s;
    __syncthreads();
    for (int off = 128; off > 0; off >>= 1) {
        if (threadIdx.x < off) red[threadIdx.x] += red[threadIdx.x + off];
        __syncthreads();
    }
    if (threadIdx.x == 0) bsum[b] = red[0];
}

__global__ void scan_bsum(const int* __restrict__ bsum, int* __restrict__ boff,
                          int* __restrict__ row_ptr) {
    __shared__ int s[128];
    int t = threadIdx.x;
    int v = (t < SCAN_NB) ? bsum[t] : 0;
    s[t] = v;
    __syncthreads();
    for (int off = 1; off < 128; off <<= 1) {
        int u = (t >= off) ? s[t - off] : 0;
        __syncthreads();
        s[t] += u;
        __syncthreads();
    }
    if (t < SCAN_NB) boff[t] = s[t] - v;
    if (t == 127) row_ptr[N_NODES] = s[127];
}

__global__ void scan_final(const int* __restrict__ counts, const int* __restrict__ boff,
                           int* __restrict__ row_ptr, int* __restrict__ cursor) {
    __shared__ int tsum[256];
    int b = blockIdx.x;
    int base = b * 1024;
    int v[4];
    int local = 0;
#pragma unroll
    for (int j = 0; j < 4; ++j) {
        int gi = base + threadIdx.x * 4 + j;
        v[j] = (gi < N_NODES) ? counts[gi] : 0;
        local += v[j];
    }
    tsum[threadIdx.x] = local;
    __syncthreads();
    for (int off = 1; off < 256; off <<= 1) {
        int u = (threadIdx.x >= off) ? tsum[threadIdx.x - off] : 0;
        __syncthreads();
        tsum[threadIdx.x] += u;
        __syncthreads();
    }
    int run = boff[b] + tsum[threadIdx.x] - local;
#pragma unroll
    for (int j = 0; j < 4; ++j) {
        int gi = base + threadIdx.x * 4 + j;
        if (gi < N_NODES) {
            row_ptr[gi] = run;
            cursor[gi] = run;
            run += v[j];
        }
    }
}

__global__ void scatter_kernel(const int* __restrict__ src, const int* __restrict__ dst,
                               int* __restrict__ cursor, int* __restrict__ srcs) {
    int e = blockIdx.x * blockDim.x + threadIdx.x;
    if (e < N_EDGES) {
        int pos = atomicAdd(&cursor[dst[e]], 1);
        srcs[pos] = src[e];
    }
}

// ---------------- h0 = relu(x @ W0)  [N,64]@[64,32] ----------------
__global__ void h0_kernel(const float* __restrict__ x, const float* __restrict__ W0,
                          float* __restrict__ h) {
    int tid = blockIdx.x * blockDim.x + threadIdx.x;
    int col = tid & 31;
    int row = tid >> 5;
    if (row >= N_NODES) return;
    const float* xr = x + row * 64;
    float acc = 0.f;
#pragma unroll
    for (int k = 0; k < 64; ++k) acc = fmaf(xr[k], W0[k * 32 + col], acc);
    h[row * 32 + col] = fmaxf(acc, 0.f);
}

// ---------------- fused xl|xr|skip matmul ----------------
// sec0 -> xl_bf (bf16), sec1 -> xr (f32), sec2 -> skip (f32, bias bs+cb)
template <int DIN>
__global__ __launch_bounds__(256) void mm3_kernel(
    const float* __restrict__ A,  // [N, DIN]
    const float* __restrict__ Wl, const float* __restrict__ Wr, const float* __restrict__ Ws,
    const float* __restrict__ bl, const float* __restrict__ br, const float* __restrict__ bs,
    const float* __restrict__ cb,
    unsigned short* __restrict__ xl_bf, float* __restrict__ xr, float* __restrict__ skip) {
    __shared__ float As[16][132];
    __shared__ float Bs[16][128];

    const int sec = blockIdx.y;  // 0=Wl,1=Wr,2=Ws
    const float* W = (sec == 0) ? Wl : (sec == 1) ? Wr : Ws;
    const int row0 = blockIdx.x * 128;
    const int tid = threadIdx.x;
    const int tx = tid & 15, ty = tid >> 4;

    float acc[8][8];
#pragma unroll
    for (int i = 0; i < 8; ++i)
#pragma unroll
        for (int j = 0; j < 8; ++j) acc[i][j] = 0.f;

    for (int k0 = 0; k0 < DIN; k0 += 16) {
#pragma unroll
        for (int i = 0; i < 2; ++i) {
            int idx = tid + i * 256;
            int kq = idx & 3;
            int r = idx >> 2;
            int row = row0 + r;
            float4 v = make_float4(0.f, 0.f, 0.f, 0.f);
            if (row < N_NODES) v = *(const float4*)&A[(size_t)row * DIN + k0 + kq * 4];
            As[kq * 4 + 0][r] = v.x;
            As[kq * 4 + 1][r] = v.y;
            As[kq * 4 + 2][r] = v.z;
            As[kq * 4 + 3][r] = v.w;
        }
#pragma unroll
        for (int i = 0; i < 2; ++i) {
            int idx = tid + i * 256;
            int c4 = idx & 31;
            int k = idx >> 5;
            *(float4*)&Bs[k][c4 * 4] = *(const float4*)&W[(k0 + k) * 128 + c4 * 4];
        }
        __syncthreads();
#pragma unroll
        for (int k = 0; k < 16; ++k) {
            float a[8], b[8];
            *(float4*)&a[0] = *(const float4*)&As[k][ty * 8];
            *(float4*)&a[4] = *(const float4*)&As[k][ty * 8 + 4];
            *(float4*)&b[0] = *(const float4*)&Bs[k][tx * 8];
            *(float4*)&b[4] = *(const float4*)&Bs[k][tx * 8 + 4];
#pragma unroll
            for (int i = 0; i < 8; ++i)
#pragma unroll
                for (int j = 0; j < 8; ++j) acc[i][j] = fmaf(a[i], b[j], acc[i][j]);
        }
        __syncthreads();
    }

    float bias[8];
#pragma unroll
    for (int j = 0; j < 8; ++j) {
        int c = tx * 8 + j;
        bias[j] = (sec == 0) ? bl[c] : (sec == 1) ? br[c] : (bs[c] + cb[c]);
    }
#pragma unroll
    for (int i = 0; i < 8; ++i) {
        int row = row0 + ty * 8 + i;
        if (row >= N_NODES) continue;
        float v[8];
#pragma unroll
        for (int j = 0; j < 8; ++j) v[j] = acc[i][j] + bias[j];
        if (sec == 0) {
            unsigned short* o = &xl_bf[(size_t)row * 128 + tx * 8];
            uint4 pk;
            pk.x = pack_bf16(v[0], v[1]);
            pk.y = pack_bf16(v[2], v[3]);
            pk.z = pack_bf16(v[4], v[5]);
            pk.w = pack_bf16(v[6], v[7]);
            *(uint4*)o = pk;
        } else {
            float* o = (sec == 1) ? &xr[(size_t)row * 128 + tx * 8]
                                  : &skip[(size_t)row * 128 + tx * 8];
            *(float4*)&o[0] = make_float4(v[0], v[1], v[2], v[3]);
            *(float4*)&o[4] = make_float4(v[4], v[5], v[6], v[7]);
        }
    }
}

// ---------------- GATv2 aggregation: one wave (64 lanes) per node ----------------
// lane covers channels (2*lane, 2*lane+1); head = lane>>4.
__global__ __launch_bounds__(256) void agg_kernel(
    const unsigned short* __restrict__ xl_bf, const float* __restrict__ xr,
    const float* __restrict__ skip, const int* __restrict__ row_ptr,
    const int* __restrict__ srcs, const float* __restrict__ att,
    float* __restrict__ out, int do_relu, int do_norm) {
    int wave = (blockIdx.x * blockDim.x + threadIdx.x) >> 6;
    int lane = threadIdx.x & 63;
    if (wave >= N_NODES) return;
    const int n = wave;
    const unsigned* xlb = (const unsigned*)xl_bf;  // one uint = 2 bf16 channels per lane

    float2 xr2 = ((const float2*)xr)[(size_t)n * 64 + lane];
    float2 at2 = ((const float2*)att)[lane];

    float l = 0.f;
    float2 acc = make_float2(0.f, 0.f);
    int beg = row_ptr[n], end = row_ptr[n + 1];
    if (beg < end) {
        unsigned vnext = xlb[(size_t)srcs[beg] * 64 + lane];
        for (int e = beg; e < end; ++e) {
            unsigned cur = vnext;
            if (e + 1 < end) vnext = xlb[(size_t)srcs[e + 1] * 64 + lane];
            float xlx = __uint_as_float(cur << 16);
            float xly = __uint_as_float(cur & 0xFFFF0000u);
            float ex = xlx + xr2.x;
            float ey = xly + xr2.y;
            float lx = fmaxf(ex, NEG_SLOPE * ex);
            float ly = fmaxf(ey, NEG_SLOPE * ey);
            float p = lx * at2.x + ly * at2.y;
            p += __shfl_xor(p, 1);
            p += __shfl_xor(p, 2);
            p += __shfl_xor(p, 4);
            p += __shfl_xor(p, 8);
            float w = __expf(p);  // scores are O(0.1): no max-subtraction needed
            l += w;
            acc.x = fmaf(xlx, w, acc.x);
            acc.y = fmaf(xly, w, acc.y);
        }
    }
    float inv = (l > 0.f) ? 1.f / l : 0.f;
    float2 sk = ((const float2*)skip)[(size_t)n * 64 + lane];
    float ox = acc.x * inv + sk.x;
    float oy = acc.y * inv + sk.y;
    if (do_relu) {
        ox = fmaxf(ox, 0.f);
        oy = fmaxf(oy, 0.f);
    }
    if (do_norm) {
        float ss = ox * ox + oy * oy;
        for (int off = 1; off < 64; off <<= 1) ss += __shfl_xor(ss, off);
        float r = 1.0f / sqrtf(ss);
        ox *= r;
        oy *= r;
    }
    ((float2*)out)[(size_t)n * 64 + lane] = make_float2(ox, oy);
}

// ---------------- launch ----------------
extern "C" void kernel_launch(void* const* d_in, const int* in_sizes, int n_in,
                              void* d_out, int out_size, void* d_ws, size_t ws_size,
                              hipStream_t stream) {
    const float* x = (const float*)d_in[0];
    const int* ei = (const int*)d_in[1];
    const int* src = ei;
    const int* dst = ei + N_EDGES;
    const float* W0 = (const float*)d_in[2];

    const float* f_p[8];
    const float* m_p[8];
    const float* l_p[8];
    for (int i = 0; i < 8; ++i) f_p[i] = (const float*)d_in[3 + i];
    for (int i = 0; i < 8; ++i) m_p[i] = (const float*)d_in[11 + i];
    for (int i = 0; i < 8; ++i) l_p[i] = (const float*)d_in[19 + i];
    // indices: 0=Wl 1=bl 2=Wr 3=br 4=att 5=cb 6=Ws 7=bs

    char* ws = (char*)d_ws;
    unsigned short* xl_bf = (unsigned short*)ws; ws += (size_t)N_NODES * 128 * 2;  // 25.6 MB
    float* xr = (float*)ws;        ws += (size_t)N_NODES * 128 * 4;  // 51.2 MB
    float* skip = (float*)ws;      ws += (size_t)N_NODES * 128 * 4;  // 51.2 MB
    float* h = (float*)ws;         ws += (size_t)N_NODES * 128 * 4;  // 51.2 MB
    int* row_ptr = (int*)ws;       ws += (size_t)(N_NODES + 1) * 4;
    int* cursor = (int*)ws;        ws += (size_t)N_NODES * 4;
    int* counts = (int*)ws;        ws += (size_t)N_NODES * 4;
    int* srcs = (int*)ws;          ws += (size_t)N_EDGES * 4;
    int* bsum = (int*)ws;          ws += (size_t)SCAN_NB * 4;
    int* boff = (int*)ws;          ws += (size_t)SCAN_NB * 4;

    hipMemsetAsync(counts, 0, (size_t)N_NODES * 4, stream);
    hist_kernel<<<(N_EDGES + 255) / 256, 256, 0, stream>>>(dst, counts);
    scan_partial<<<SCAN_NB, 256, 0, stream>>>(counts, bsum);
    scan_bsum<<<1, 128, 0, stream>>>(bsum, boff, row_ptr);
    scan_final<<<SCAN_NB, 256, 0, stream>>>(counts, boff, row_ptr, cursor);
    scatter_kernel<<<(N_EDGES + 255) / 256, 256, 0, stream>>>(src, dst, cursor, srcs);

    h0_kernel<<<(N_NODES * 32) / 256, 256, 0, stream>>>(x, W0, h);

    dim3 gmm((N_NODES + 127) / 128, 3);
    const int gagg = (N_NODES * 64) / 256;
    float* out = (float*)d_out;

    // layer f (din=32), relu
    mm3_kernel<32><<<gmm, 256, 0, stream>>>(h, f_p[0], f_p[2], f_p[6], f_p[1], f_p[3],
                                            f_p[7], f_p[5], xl_bf, xr, skip);
    agg_kernel<<<gagg, 256, 0, stream>>>(xl_bf, xr, skip, row_ptr, srcs, f_p[4], h, 1, 0);

    // 3x layer m (din=128, shared weights), relu
    for (int it = 0; it < 3; ++it) {
        mm3_kernel<128><<<gmm, 256, 0, stream>>>(h, m_p[0], m_p[2], m_p[6], m_p[1], m_p[3],
                                                 m_p[7], m_p[5], xl_bf, xr, skip);
        agg_kernel<<<gagg, 256, 0, stream>>>(xl_bf, xr, skip, row_ptr, srcs, m_p[4], h, 1, 0);
    }

    // layer l (din=128), no relu, L2 normalize, write to d_out
    mm3_kernel<128><<<gmm, 256, 0, stream>>>(h, l_p[0], l_p[2], l_p[6], l_p[1], l_p[3],
                                             l_p[7], l_p[5], xl_bf, xr, skip);
    agg_kernel<<<gagg, 256, 0, stream>>>(xl_bf, xr, skip, row_ptr, srcs, l_p[4], out, 0, 1);
}

// Round 4
// 1297.859 us; speedup vs baseline: 1.2107x; 1.2107x over previous
//
#include <hip/hip_runtime.h>
#include <hip/hip_bf16.h>
#include <math.h>

#define N_NODES 100000
#define N_EDGES 1000000
#define NEG_SLOPE 0.2f
#define SCAN_NB 98  // ceil(100000/1024)

typedef short v8s __attribute__((ext_vector_type(8)));
typedef float v4f __attribute__((ext_vector_type(4)));

__device__ inline unsigned pack_bf16(float a, float b) {
    unsigned ua = __float_as_uint(a);
    unsigned ub = __float_as_uint(b);
    ua = (ua + 0x7FFFu + ((ua >> 16) & 1u)) >> 16;
    ub = (ub + 0x7FFFu + ((ub >> 16) & 1u)) >> 16;
    return ua | (ub << 16);
}
__device__ inline unsigned short bf16_rn(float x) {
    unsigned u = __float_as_uint(x);
    u = (u + 0x7FFFu + ((u >> 16) & 1u)) >> 16;
    return (unsigned short)u;
}

// ---------------- CSR build ----------------
__global__ void hist_kernel(const int* __restrict__ dst, int* __restrict__ counts) {
    int e = blockIdx.x * blockDim.x + threadIdx.x;
    if (e < N_EDGES) atomicAdd(&counts[dst[e]], 1);
}

__global__ void scan_partial(const int* __restrict__ counts, int* __restrict__ bsum) {
    __shared__ int red[256];
    int b = blockIdx.x;
    int base = b * 1024;
    int s = 0;
    for (int i = threadIdx.x; i < 1024; i += 256) {
        int gi = base + i;
        s += (gi < N_NODES) ? counts[gi] : 0;
    }
    red[threadIdx.x] = s;
    __syncthreads();
    for (int off = 128; off > 0; off >>= 1) {
        if (threadIdx.x < off) red[threadIdx.x] += red[threadIdx.x + off];
        __syncthreads();
    }
    if (threadIdx.x == 0) bsum[b] = red[0];
}

__global__ void scan_bsum(const int* __restrict__ bsum, int* __restrict__ boff,
                          int* __restrict__ row_ptr) {
    __shared__ int s[128];
    int t = threadIdx.x;
    int v = (t < SCAN_NB) ? bsum[t] : 0;
    s[t] = v;
    __syncthreads();
    for (int off = 1; off < 128; off <<= 1) {
        int u = (t >= off) ? s[t - off] : 0;
        __syncthreads();
        s[t] += u;
        __syncthreads();
    }
    if (t < SCAN_NB) boff[t] = s[t] - v;
    if (t == 127) row_ptr[N_NODES] = s[127];
}

__global__ void scan_final(const int* __restrict__ counts, const int* __restrict__ boff,
                           int* __restrict__ row_ptr, int* __restrict__ cursor) {
    __shared__ int tsum[256];
    int b = blockIdx.x;
    int base = b * 1024;
    int v[4];
    int local = 0;
#pragma unroll
    for (int j = 0; j < 4; ++j) {
        int gi = base + threadIdx.x * 4 + j;
        v[j] = (gi < N_NODES) ? counts[gi] : 0;
        local += v[j];
    }
    tsum[threadIdx.x] = local;
    __syncthreads();
    for (int off = 1; off < 256; off <<= 1) {
        int u = (threadIdx.x >= off) ? tsum[threadIdx.x - off] : 0;
        __syncthreads();
        tsum[threadIdx.x] += u;
        __syncthreads();
    }
    int run = boff[b] + tsum[threadIdx.x] - local;
#pragma unroll
    for (int j = 0; j < 4; ++j) {
        int gi = base + threadIdx.x * 4 + j;
        if (gi < N_NODES) {
            row_ptr[gi] = run;
            cursor[gi] = run;
            run += v[j];
        }
    }
}

__global__ void scatter_kernel(const int* __restrict__ src, const int* __restrict__ dst,
                               int* __restrict__ cursor, int* __restrict__ srcs) {
    int e = blockIdx.x * blockDim.x + threadIdx.x;
    if (e < N_EDGES) {
        int pos = atomicAdd(&cursor[dst[e]], 1);
        srcs[pos] = src[e];
    }
}

// ---------------- weight convert: Wt[n=0..383][k=0..K-1] = W_sec[k*128 + n&127] (bf16)
template <int K>
__global__ void convert_w(const float* __restrict__ Wl, const float* __restrict__ Wr,
                          const float* __restrict__ Ws, unsigned short* __restrict__ wt) {
    int idx = blockIdx.x * blockDim.x + threadIdx.x;
    if (idx >= 384 * K) return;
    int n = idx / K;
    int k = idx - n * K;
    int sec = n >> 7;
    int nn = n & 127;
    const float* W = (sec == 0) ? Wl : (sec == 1) ? Wr : Ws;
    wt[idx] = bf16_rn(W[k * 128 + nn]);
}

// ---------------- h0 = relu(x @ W0) -> bf16 [N,32] ----------------
__global__ void h0_kernel(const float* __restrict__ x, const float* __restrict__ W0,
                          unsigned short* __restrict__ h) {
    int tid = blockIdx.x * blockDim.x + threadIdx.x;
    int col = tid & 31;
    int row = tid >> 5;
    if (row >= N_NODES) return;
    const float* xr = x + row * 64;
    float acc = 0.f;
#pragma unroll
    for (int k = 0; k < 64; ++k) acc = fmaf(xr[k], W0[k * 32 + col], acc);
    h[row * 32 + col] = bf16_rn(fmaxf(acc, 0.f));
}

// ---------------- MFMA mm3: [N,K]bf16 @ Wt^T -> xl_bf16 | xr f32 | skip f32 ----------------
// grid (ceil(N/256), 6); blockIdx.y: sec = y>>1, col-half = y&1. 4 waves/block, wave = 64 rows x 64 cols.
// No LDS, no barriers: a/b frags straight from global (16 B/lane).
template <int K>
__global__ __launch_bounds__(256) void mm3_mfma(
    const unsigned short* __restrict__ A, const unsigned short* __restrict__ Wt,
    const float* __restrict__ bl, const float* __restrict__ br, const float* __restrict__ bs,
    const float* __restrict__ cb,
    unsigned short* __restrict__ xl_bf, float* __restrict__ xr, float* __restrict__ skip) {
    const int tid = threadIdx.x;
    const int wave = tid >> 6;
    const int lane = tid & 63;
    const int q = lane >> 4;    // quad
    const int li = lane & 15;
    const int r0 = blockIdx.x * 256 + wave * 64;
    const int sec = blockIdx.y >> 1;
    const int c0 = (blockIdx.y & 1) * 64;  // col offset within the 128-wide section

    v4f acc[4][4];
#pragma unroll
    for (int mi = 0; mi < 4; ++mi)
#pragma unroll
        for (int ni = 0; ni < 4; ++ni) acc[mi][ni] = (v4f)(0.f);

#pragma unroll
    for (int k0 = 0; k0 < K; k0 += 32) {
        v8s a[4], b[4];
#pragma unroll
        for (int mi = 0; mi < 4; ++mi) {
            int row = r0 + mi * 16 + li;
            row = row < N_NODES ? row : N_NODES - 1;
            a[mi] = *(const v8s*)&A[(size_t)row * K + k0 + q * 8];
        }
#pragma unroll
        for (int ni = 0; ni < 4; ++ni) {
            int col = sec * 128 + c0 + ni * 16 + li;  // global col 0..383
            b[ni] = *(const v8s*)&Wt[(size_t)col * K + k0 + q * 8];
        }
#pragma unroll
        for (int mi = 0; mi < 4; ++mi)
#pragma unroll
            for (int ni = 0; ni < 4; ++ni)
                acc[mi][ni] = __builtin_amdgcn_mfma_f32_16x16x32_bf16(a[mi], b[ni], acc[mi][ni], 0, 0, 0);
    }

#pragma unroll
    for (int ni = 0; ni < 4; ++ni) {
        int cl = c0 + ni * 16 + li;  // col within the section, 0..127
        float bias = (sec == 0) ? bl[cl] : (sec == 1) ? br[cl] : (bs[cl] + cb[cl]);
#pragma unroll
        for (int mi = 0; mi < 4; ++mi)
#pragma unroll
            for (int r = 0; r < 4; ++r) {
                int row = r0 + mi * 16 + q * 4 + r;
                if (row >= N_NODES) continue;
                float v = acc[mi][ni][r] + bias;
                if (sec == 0)
                    xl_bf[(size_t)row * 128 + cl] = bf16_rn(v);
                else if (sec == 1)
                    xr[(size_t)row * 128 + cl] = v;
                else
                    skip[(size_t)row * 128 + cl] = v;
            }
    }
}

// ---------------- GATv2 aggregation: one wave per node ----------------
__global__ __launch_bounds__(256) void agg_kernel(
    const unsigned short* __restrict__ xl_bf, const float* __restrict__ xr,
    const float* __restrict__ skip, const int* __restrict__ row_ptr,
    const int* __restrict__ srcs, const float* __restrict__ att,
    unsigned* __restrict__ out_bf, float* __restrict__ out_f,
    int write_bf, int do_relu, int do_norm) {
    int wave = (blockIdx.x * blockDim.x + threadIdx.x) >> 6;
    int lane = threadIdx.x & 63;
    if (wave >= N_NODES) return;
    const int n = wave;
    const unsigned* xlb = (const unsigned*)xl_bf;

    float2 xr2 = ((const float2*)xr)[(size_t)n * 64 + lane];
    float2 at2 = ((const float2*)att)[lane];

    float l = 0.f;
    float2 acc = make_float2(0.f, 0.f);
    int beg = row_ptr[n], end = row_ptr[n + 1];
    if (beg < end) {
        unsigned vnext = xlb[(size_t)srcs[beg] * 64 + lane];
        for (int e = beg; e < end; ++e) {
            unsigned cur = vnext;
            if (e + 1 < end) vnext = xlb[(size_t)srcs[e + 1] * 64 + lane];
            float xlx = __uint_as_float(cur << 16);
            float xly = __uint_as_float(cur & 0xFFFF0000u);
            float ex = xlx + xr2.x;
            float ey = xly + xr2.y;
            float lx = fmaxf(ex, NEG_SLOPE * ex);
            float ly = fmaxf(ey, NEG_SLOPE * ey);
            float p = lx * at2.x + ly * at2.y;
            p += __shfl_xor(p, 1);
            p += __shfl_xor(p, 2);
            p += __shfl_xor(p, 4);
            p += __shfl_xor(p, 8);
            float w = __expf(p);  // scores are O(0.1): max-subtraction unnecessary
            l += w;
            acc.x = fmaf(xlx, w, acc.x);
            acc.y = fmaf(xly, w, acc.y);
        }
    }
    float inv = (l > 0.f) ? 1.f / l : 0.f;
    float2 sk = ((const float2*)skip)[(size_t)n * 64 + lane];
    float ox = acc.x * inv + sk.x;
    float oy = acc.y * inv + sk.y;
    if (do_relu) {
        ox = fmaxf(ox, 0.f);
        oy = fmaxf(oy, 0.f);
    }
    if (do_norm) {
        float ss = ox * ox + oy * oy;
        for (int off = 1; off < 64; off <<= 1) ss += __shfl_xor(ss, off);
        float r = 1.0f / sqrtf(ss);
        ox *= r;
        oy *= r;
    }
    if (write_bf)
        out_bf[(size_t)n * 64 + lane] = pack_bf16(ox, oy);
    else
        ((float2*)out_f)[(size_t)n * 64 + lane] = make_float2(ox, oy);
}

// ---------------- launch ----------------
extern "C" void kernel_launch(void* const* d_in, const int* in_sizes, int n_in,
                              void* d_out, int out_size, void* d_ws, size_t ws_size,
                              hipStream_t stream) {
    const float* x = (const float*)d_in[0];
    const int* ei = (const int*)d_in[1];
    const int* src = ei;
    const int* dst = ei + N_EDGES;
    const float* W0 = (const float*)d_in[2];

    const float* f_p[8];
    const float* m_p[8];
    const float* l_p[8];
    for (int i = 0; i < 8; ++i) f_p[i] = (const float*)d_in[3 + i];
    for (int i = 0; i < 8; ++i) m_p[i] = (const float*)d_in[11 + i];
    for (int i = 0; i < 8; ++i) l_p[i] = (const float*)d_in[19 + i];
    // indices: 0=Wl 1=bl 2=Wr 3=br 4=att 5=cb 6=Ws 7=bs

    char* ws = (char*)d_ws;
    unsigned short* xl_bf = (unsigned short*)ws; ws += (size_t)N_NODES * 128 * 2;  // 25.6 MB
    float* xr = (float*)ws;        ws += (size_t)N_NODES * 128 * 4;  // 51.2 MB
    float* skip = (float*)ws;      ws += (size_t)N_NODES * 128 * 4;  // 51.2 MB
    unsigned short* h_bf = (unsigned short*)ws; ws += (size_t)N_NODES * 128 * 2;  // 25.6 MB
    int* row_ptr = (int*)ws;       ws += (size_t)(N_NODES + 1) * 4;
    int* cursor = (int*)ws;        ws += (size_t)N_NODES * 4;
    int* counts = (int*)ws;        ws += (size_t)N_NODES * 4;
    int* srcs = (int*)ws;          ws += (size_t)N_EDGES * 4;
    int* bsum = (int*)ws;          ws += (size_t)SCAN_NB * 4;
    int* boff = (int*)ws;          ws += (size_t)SCAN_NB * 4;
    unsigned short* wt_f = (unsigned short*)ws; ws += (size_t)384 * 32 * 2;
    unsigned short* wt_m = (unsigned short*)ws; ws += (size_t)384 * 128 * 2;
    unsigned short* wt_l = (unsigned short*)ws; ws += (size_t)384 * 128 * 2;

    hipMemsetAsync(counts, 0, (size_t)N_NODES * 4, stream);
    hist_kernel<<<(N_EDGES + 255) / 256, 256, 0, stream>>>(dst, counts);
    scan_partial<<<SCAN_NB, 256, 0, stream>>>(counts, bsum);
    scan_bsum<<<1, 128, 0, stream>>>(bsum, boff, row_ptr);
    scan_final<<<SCAN_NB, 256, 0, stream>>>(counts, boff, row_ptr, cursor);
    scatter_kernel<<<(N_EDGES + 255) / 256, 256, 0, stream>>>(src, dst, cursor, srcs);

    convert_w<32><<<(384 * 32 + 255) / 256, 256, 0, stream>>>(f_p[0], f_p[2], f_p[6], wt_f);
    convert_w<128><<<(384 * 128 + 255) / 256, 256, 0, stream>>>(m_p[0], m_p[2], m_p[6], wt_m);
    convert_w<128><<<(384 * 128 + 255) / 256, 256, 0, stream>>>(l_p[0], l_p[2], l_p[6], wt_l);

    h0_kernel<<<(N_NODES * 32) / 256, 256, 0, stream>>>(x, W0, h_bf);

    dim3 gmm((N_NODES + 255) / 256, 6);
    const int gagg = (N_NODES * 64) / 256;
    float* out = (float*)d_out;

    // layer f (din=32), relu
    mm3_mfma<32><<<gmm, 256, 0, stream>>>(h_bf, wt_f, f_p[1], f_p[3], f_p[7], f_p[5],
                                          xl_bf, xr, skip);
    agg_kernel<<<gagg, 256, 0, stream>>>(xl_bf, xr, skip, row_ptr, srcs, f_p[4],
                                         (unsigned*)h_bf, nullptr, 1, 1, 0);

    // 3x layer m (din=128, shared weights), relu
    for (int it = 0; it < 3; ++it) {
        mm3_mfma<128><<<gmm, 256, 0, stream>>>(h_bf, wt_m, m_p[1], m_p[3], m_p[7], m_p[5],
                                               xl_bf, xr, skip);
        agg_kernel<<<gagg, 256, 0, stream>>>(xl_bf, xr, skip, row_ptr, srcs, m_p[4],
                                             (unsigned*)h_bf, nullptr, 1, 1, 0);
    }

    // layer l (din=128), no relu, L2 normalize, write fp32 to d_out
    mm3_mfma<128><<<gmm, 256, 0, stream>>>(h_bf, wt_l, l_p[1], l_p[3], l_p[7], l_p[5],
                                           xl_bf, xr, skip);
    agg_kernel<<<gagg, 256, 0, stream>>>(xl_bf, xr, skip, row_ptr, srcs, l_p[4],
                                         nullptr, out, 0, 0, 1);
}

// Round 5
// 1001.745 us; speedup vs baseline: 1.5686x; 1.2956x over previous
//
#include <hip/hip_runtime.h>
#include <hip/hip_bf16.h>
#include <math.h>

#define N_NODES 100000
#define N_EDGES 1000000
#define NEG_SLOPE 0.2f
#define SCAN_NB 98  // ceil(100000/1024)

typedef short v8s __attribute__((ext_vector_type(8)));
typedef float v4f __attribute__((ext_vector_type(4)));

__device__ inline unsigned pack_bf16(float a, float b) {
    unsigned ua = __float_as_uint(a);
    unsigned ub = __float_as_uint(b);
    ua = (ua + 0x7FFFu + ((ua >> 16) & 1u)) >> 16;
    ub = (ub + 0x7FFFu + ((ub >> 16) & 1u)) >> 16;
    return ua | (ub << 16);
}
__device__ inline unsigned short bf16_rn(float x) {
    unsigned u = __float_as_uint(x);
    u = (u + 0x7FFFu + ((u >> 16) & 1u)) >> 16;
    return (unsigned short)u;
}
__device__ inline float2 unpk(unsigned u) {
    return make_float2(__uint_as_float(u << 16), __uint_as_float(u & 0xFFFF0000u));
}

// ---------------- CSR build ----------------
__global__ void hist_kernel(const int* __restrict__ dst, int* __restrict__ counts) {
    int e = blockIdx.x * blockDim.x + threadIdx.x;
    if (e < N_EDGES) atomicAdd(&counts[dst[e]], 1);
}

__global__ void scan_partial(const int* __restrict__ counts, int* __restrict__ bsum) {
    __shared__ int red[256];
    int b = blockIdx.x;
    int base = b * 1024;
    int s = 0;
    for (int i = threadIdx.x; i < 1024; i += 256) {
        int gi = base + i;
        s += (gi < N_NODES) ? counts[gi] : 0;
    }
    red[threadIdx.x] = s;
    __syncthreads();
    for (int off = 128; off > 0; off >>= 1) {
        if (threadIdx.x < off) red[threadIdx.x] += red[threadIdx.x + off];
        __syncthreads();
    }
    if (threadIdx.x == 0) bsum[b] = red[0];
}

__global__ void scan_bsum(const int* __restrict__ bsum, int* __restrict__ boff,
                          int* __restrict__ row_ptr) {
    __shared__ int s[128];
    int t = threadIdx.x;
    int v = (t < SCAN_NB) ? bsum[t] : 0;
    s[t] = v;
    __syncthreads();
    for (int off = 1; off < 128; off <<= 1) {
        int u = (t >= off) ? s[t - off] : 0;
        __syncthreads();
        s[t] += u;
        __syncthreads();
    }
    if (t < SCAN_NB) boff[t] = s[t] - v;
    if (t == 127) row_ptr[N_NODES] = s[127];
}

__global__ void scan_final(const int* __restrict__ counts, const int* __restrict__ boff,
                           int* __restrict__ row_ptr, int* __restrict__ cursor) {
    __shared__ int tsum[256];
    int b = blockIdx.x;
    int base = b * 1024;
    int v[4];
    int local = 0;
#pragma unroll
    for (int j = 0; j < 4; ++j) {
        int gi = base + threadIdx.x * 4 + j;
        v[j] = (gi < N_NODES) ? counts[gi] : 0;
        local += v[j];
    }
    tsum[threadIdx.x] = local;
    __syncthreads();
    for (int off = 1; off < 256; off <<= 1) {
        int u = (threadIdx.x >= off) ? tsum[threadIdx.x - off] : 0;
        __syncthreads();
        tsum[threadIdx.x] += u;
        __syncthreads();
    }
    int run = boff[b] + tsum[threadIdx.x] - local;
#pragma unroll
    for (int j = 0; j < 4; ++j) {
        int gi = base + threadIdx.x * 4 + j;
        if (gi < N_NODES) {
            row_ptr[gi] = run;
            cursor[gi] = run;
            run += v[j];
        }
    }
}

__global__ void scatter_kernel(const int* __restrict__ src, const int* __restrict__ dst,
                               int* __restrict__ cursor, int* __restrict__ srcs) {
    int e = blockIdx.x * blockDim.x + threadIdx.x;
    if (e < N_EDGES) {
        int pos = atomicAdd(&cursor[dst[e]], 1);
        srcs[pos] = src[e];
    }
}

// ---------------- weight convert: Wt[n=0..383][k] = W_sec[k*128 + n&127] (bf16)
template <int K>
__global__ void convert_w(const float* __restrict__ Wl, const float* __restrict__ Wr,
                          const float* __restrict__ Ws, unsigned short* __restrict__ wt) {
    int idx = blockIdx.x * blockDim.x + threadIdx.x;
    if (idx >= 384 * K) return;
    int n = idx / K;
    int k = idx - n * K;
    int sec = n >> 7;
    int nn = n & 127;
    const float* W = (sec == 0) ? Wl : (sec == 1) ? Wr : Ws;
    wt[idx] = bf16_rn(W[k * 128 + nn]);
}

// ---------------- h0 = relu(x @ W0) -> bf16 [N,32] ----------------
__global__ void h0_kernel(const float* __restrict__ x, const float* __restrict__ W0,
                          unsigned short* __restrict__ h) {
    int tid = blockIdx.x * blockDim.x + threadIdx.x;
    int col = tid & 31;
    int row = tid >> 5;
    if (row >= N_NODES) return;
    const float* xr = x + row * 64;
    float acc = 0.f;
#pragma unroll
    for (int k = 0; k < 64; ++k) acc = fmaf(xr[k], W0[k * 32 + col], acc);
    h[row * 32 + col] = bf16_rn(fmaxf(acc, 0.f));
}

// ---------------- MFMA mm3: [N,K]bf16 @ Wt^T -> xl|xr|skip all bf16 ----------------
template <int K>
__global__ __launch_bounds__(256) void mm3_mfma(
    const unsigned short* __restrict__ A, const unsigned short* __restrict__ Wt,
    const float* __restrict__ bl, const float* __restrict__ br, const float* __restrict__ bs,
    const float* __restrict__ cb,
    unsigned short* __restrict__ xl_bf, unsigned short* __restrict__ xr_bf,
    unsigned short* __restrict__ sk_bf) {
    const int tid = threadIdx.x;
    const int wave = tid >> 6;
    const int lane = tid & 63;
    const int q = lane >> 4;
    const int li = lane & 15;
    const int r0 = blockIdx.x * 256 + wave * 64;
    const int sec = blockIdx.y >> 1;
    const int c0 = (blockIdx.y & 1) * 64;

    v4f acc[4][4];
#pragma unroll
    for (int mi = 0; mi < 4; ++mi)
#pragma unroll
        for (int ni = 0; ni < 4; ++ni) acc[mi][ni] = (v4f)(0.f);

#pragma unroll
    for (int k0 = 0; k0 < K; k0 += 32) {
        v8s a[4], b[4];
#pragma unroll
        for (int mi = 0; mi < 4; ++mi) {
            int row = r0 + mi * 16 + li;
            row = row < N_NODES ? row : N_NODES - 1;
            a[mi] = *(const v8s*)&A[(size_t)row * K + k0 + q * 8];
        }
#pragma unroll
        for (int ni = 0; ni < 4; ++ni) {
            int col = sec * 128 + c0 + ni * 16 + li;
            b[ni] = *(const v8s*)&Wt[(size_t)col * K + k0 + q * 8];
        }
#pragma unroll
        for (int mi = 0; mi < 4; ++mi)
#pragma unroll
            for (int ni = 0; ni < 4; ++ni)
                acc[mi][ni] = __builtin_amdgcn_mfma_f32_16x16x32_bf16(a[mi], b[ni], acc[mi][ni], 0, 0, 0);
    }

    unsigned short* dstp = (sec == 0) ? xl_bf : (sec == 1) ? xr_bf : sk_bf;
#pragma unroll
    for (int ni = 0; ni < 4; ++ni) {
        int cl = c0 + ni * 16 + li;
        float bias = (sec == 0) ? bl[cl] : (sec == 1) ? br[cl] : (bs[cl] + cb[cl]);
#pragma unroll
        for (int mi = 0; mi < 4; ++mi)
#pragma unroll
            for (int r = 0; r < 4; ++r) {
                int row = r0 + mi * 16 + q * 4 + r;
                if (row >= N_NODES) continue;
                dstp[(size_t)row * 128 + cl] = bf16_rn(acc[mi][ni][r] + bias);
            }
    }
}

// ---------------- GATv2 aggregation: one wave per node, edge loop unrolled x4 ----------------
#define EDGE_BODY(U, L, AX, AY)                                        \
    {                                                                  \
        float2 xl2 = unpk(U);                                          \
        float ex = xl2.x + xr2.x;                                      \
        float ey = xl2.y + xr2.y;                                      \
        float lx = fmaxf(ex, NEG_SLOPE * ex);                          \
        float ly = fmaxf(ey, NEG_SLOPE * ey);                          \
        float p = lx * at2.x + ly * at2.y;                             \
        p += __shfl_xor(p, 1);                                         \
        p += __shfl_xor(p, 2);                                         \
        p += __shfl_xor(p, 4);                                         \
        p += __shfl_xor(p, 8);                                         \
        float w = __expf(p);                                           \
        L += w;                                                        \
        AX = fmaf(xl2.x, w, AX);                                       \
        AY = fmaf(xl2.y, w, AY);                                       \
    }

__global__ __launch_bounds__(256) void agg_kernel(
    const unsigned* __restrict__ xlb, const unsigned* __restrict__ xrb,
    const unsigned* __restrict__ skb, const int* __restrict__ row_ptr,
    const int* __restrict__ srcs, const float* __restrict__ att,
    unsigned* __restrict__ out_bf, float* __restrict__ out_f,
    int write_bf, int do_relu, int do_norm) {
    int wave = (blockIdx.x * blockDim.x + threadIdx.x) >> 6;
    int lane = threadIdx.x & 63;
    if (wave >= N_NODES) return;
    const int n = wave;

    float2 xr2 = unpk(xrb[(size_t)n * 64 + lane]);
    float2 at2 = ((const float2*)att)[lane];

    float l0 = 0.f, l1 = 0.f, l2 = 0.f, l3 = 0.f;
    float ax0 = 0.f, ay0 = 0.f, ax1 = 0.f, ay1 = 0.f;
    float ax2 = 0.f, ay2 = 0.f, ax3 = 0.f, ay3 = 0.f;

    int beg = row_ptr[n], end = row_ptr[n + 1];
    int e = beg;
    for (; e + 4 <= end; e += 4) {
        int s0 = srcs[e], s1 = srcs[e + 1], s2 = srcs[e + 2], s3 = srcs[e + 3];
        unsigned u0 = xlb[(size_t)s0 * 64 + lane];
        unsigned u1 = xlb[(size_t)s1 * 64 + lane];
        unsigned u2 = xlb[(size_t)s2 * 64 + lane];
        unsigned u3 = xlb[(size_t)s3 * 64 + lane];
        EDGE_BODY(u0, l0, ax0, ay0);
        EDGE_BODY(u1, l1, ax1, ay1);
        EDGE_BODY(u2, l2, ax2, ay2);
        EDGE_BODY(u3, l3, ax3, ay3);
    }
    for (; e < end; ++e) {
        unsigned u = xlb[(size_t)srcs[e] * 64 + lane];
        EDGE_BODY(u, l0, ax0, ay0);
    }
    float l = (l0 + l1) + (l2 + l3);
    float accx = (ax0 + ax1) + (ax2 + ax3);
    float accy = (ay0 + ay1) + (ay2 + ay3);

    float inv = (l > 0.f) ? 1.f / l : 0.f;
    float2 sk = unpk(skb[(size_t)n * 64 + lane]);
    float ox = accx * inv + sk.x;
    float oy = accy * inv + sk.y;
    if (do_relu) {
        ox = fmaxf(ox, 0.f);
        oy = fmaxf(oy, 0.f);
    }
    if (do_norm) {
        float ss = ox * ox + oy * oy;
        for (int off = 1; off < 64; off <<= 1) ss += __shfl_xor(ss, off);
        float r = 1.0f / sqrtf(ss);
        ox *= r;
        oy *= r;
    }
    if (write_bf)
        out_bf[(size_t)n * 64 + lane] = pack_bf16(ox, oy);
    else
        ((float2*)out_f)[(size_t)n * 64 + lane] = make_float2(ox, oy);
}

// ---------------- launch ----------------
extern "C" void kernel_launch(void* const* d_in, const int* in_sizes, int n_in,
                              void* d_out, int out_size, void* d_ws, size_t ws_size,
                              hipStream_t stream) {
    const float* x = (const float*)d_in[0];
    const int* ei = (const int*)d_in[1];
    const int* src = ei;
    const int* dst = ei + N_EDGES;
    const float* W0 = (const float*)d_in[2];

    const float* f_p[8];
    const float* m_p[8];
    const float* l_p[8];
    for (int i = 0; i < 8; ++i) f_p[i] = (const float*)d_in[3 + i];
    for (int i = 0; i < 8; ++i) m_p[i] = (const float*)d_in[11 + i];
    for (int i = 0; i < 8; ++i) l_p[i] = (const float*)d_in[19 + i];
    // indices: 0=Wl 1=bl 2=Wr 3=br 4=att 5=cb 6=Ws 7=bs

    char* ws = (char*)d_ws;
    unsigned short* xl_bf = (unsigned short*)ws; ws += (size_t)N_NODES * 128 * 2;  // 25.6 MB
    unsigned short* xr_bf = (unsigned short*)ws; ws += (size_t)N_NODES * 128 * 2;
    unsigned short* sk_bf = (unsigned short*)ws; ws += (size_t)N_NODES * 128 * 2;
    unsigned short* h_bf = (unsigned short*)ws;  ws += (size_t)N_NODES * 128 * 2;
    int* row_ptr = (int*)ws;       ws += (size_t)(N_NODES + 1) * 4;
    int* cursor = (int*)ws;        ws += (size_t)N_NODES * 4;
    int* counts = (int*)ws;        ws += (size_t)N_NODES * 4;
    int* srcs = (int*)ws;          ws += (size_t)N_EDGES * 4;
    int* bsum = (int*)ws;          ws += (size_t)SCAN_NB * 4;
    int* boff = (int*)ws;          ws += (size_t)SCAN_NB * 4;
    unsigned short* wt_f = (unsigned short*)ws; ws += (size_t)384 * 32 * 2;
    unsigned short* wt_m = (unsigned short*)ws; ws += (size_t)384 * 128 * 2;
    unsigned short* wt_l = (unsigned short*)ws; ws += (size_t)384 * 128 * 2;

    hipMemsetAsync(counts, 0, (size_t)N_NODES * 4, stream);
    hist_kernel<<<(N_EDGES + 255) / 256, 256, 0, stream>>>(dst, counts);
    scan_partial<<<SCAN_NB, 256, 0, stream>>>(counts, bsum);
    scan_bsum<<<1, 128, 0, stream>>>(bsum, boff, row_ptr);
    scan_final<<<SCAN_NB, 256, 0, stream>>>(counts, boff, row_ptr, cursor);
    scatter_kernel<<<(N_EDGES + 255) / 256, 256, 0, stream>>>(src, dst, cursor, srcs);

    convert_w<32><<<(384 * 32 + 255) / 256, 256, 0, stream>>>(f_p[0], f_p[2], f_p[6], wt_f);
    convert_w<128><<<(384 * 128 + 255) / 256, 256, 0, stream>>>(m_p[0], m_p[2], m_p[6], wt_m);
    convert_w<128><<<(384 * 128 + 255) / 256, 256, 0, stream>>>(l_p[0], l_p[2], l_p[6], wt_l);

    h0_kernel<<<(N_NODES * 32) / 256, 256, 0, stream>>>(x, W0, h_bf);

    dim3 gmm((N_NODES + 255) / 256, 6);
    const int gagg = (N_NODES * 64) / 256;
    float* out = (float*)d_out;

    // layer f (din=32), relu
    mm3_mfma<32><<<gmm, 256, 0, stream>>>(h_bf, wt_f, f_p[1], f_p[3], f_p[7], f_p[5],
                                          xl_bf, xr_bf, sk_bf);
    agg_kernel<<<gagg, 256, 0, stream>>>((unsigned*)xl_bf, (unsigned*)xr_bf, (unsigned*)sk_bf,
                                         row_ptr, srcs, f_p[4],
                                         (unsigned*)h_bf, nullptr, 1, 1, 0);

    // 3x layer m (din=128, shared weights), relu
    for (int it = 0; it < 3; ++it) {
        mm3_mfma<128><<<gmm, 256, 0, stream>>>(h_bf, wt_m, m_p[1], m_p[3], m_p[7], m_p[5],
                                               xl_bf, xr_bf, sk_bf);
        agg_kernel<<<gagg, 256, 0, stream>>>((unsigned*)xl_bf, (unsigned*)xr_bf, (unsigned*)sk_bf,
                                             row_ptr, srcs, m_p[4],
                                             (unsigned*)h_bf, nullptr, 1, 1, 0);
    }

    // layer l (din=128), no relu, L2 normalize, write fp32 to d_out
    mm3_mfma<128><<<gmm, 256, 0, stream>>>(h_bf, wt_l, l_p[1], l_p[3], l_p[7], l_p[5],
                                           xl_bf, xr_bf, sk_bf);
    agg_kernel<<<gagg, 256, 0, stream>>>((unsigned*)xl_bf, (unsigned*)xr_bf, (unsigned*)sk_bf,
                                         row_ptr, srcs, l_p[4],
                                         nullptr, out, 0, 0, 1);
}